// Round 1
// baseline (83.140 us; speedup 1.0000x reference)
//
#include <hip/hip_runtime.h>
#include <hip/hip_bf16.h>

#define SPATIAL_SCALE 0.125f
#define POOLED 7
#define PART 7
#define SAMPLES 4
#define TRANS_STD 0.1f

#define B_DIM 4
#define C_DIM 256
#define H_DIM 64
#define W_DIM 64
#define BINS (POOLED * POOLED)   // 49
#define CH 128                   // channels per pool block (half)
#define NB0 25                   // bins in group g=0 (bins 0..24)
#define NB1 24                   // bins in group g=1 (bins 25..48)
#define DESC_DW 20               // LDS descriptor stride: rowbase, pad x3, w[16]

typedef unsigned short ushort_t;
typedef unsigned int   uint_t;

// round-to-nearest-even fp32 -> bf16 (manual; finite inputs)
__device__ __forceinline__ ushort_t f2bf_rne(float f) {
    uint_t x = __float_as_uint(f);
    x += 0x7FFFu + ((x >> 16) & 1u);
    return (ushort_t)(x >> 16);
}

// ---------------------------------------------------------------------------
// NCHW fp32 -> NHWC bf16 transpose (proven R9; ~24 MB traffic, ~4.5 us)
// ---------------------------------------------------------------------------
#define TS 32
__global__ __launch_bounds__(256) void nchw_to_nhwc_bf16(const float* __restrict__ in,
                                                         ushort_t* __restrict__ out) {
    __shared__ float tile[TS][TS + 1];
    const int b   = blockIdx.z;
    const int hw0 = blockIdx.x * TS;
    const int c0  = blockIdx.y * TS;
    const int tx  = threadIdx.x;
    const int ty  = threadIdx.y;

    const float* inb  = in  + (size_t)b * C_DIM * (H_DIM * W_DIM);
    ushort_t*    outb = out + (size_t)b * (H_DIM * W_DIM) * C_DIM;

    #pragma unroll
    for (int i = ty; i < TS; i += 8)
        tile[i][tx] = inb[(size_t)(c0 + i) * (H_DIM * W_DIM) + (hw0 + tx)];
    __syncthreads();
    #pragma unroll
    for (int i = ty; i < TS; i += 8)
        outb[(size_t)(hw0 + i) * C_DIM + (c0 + tx)] = f2bf_rne(tile[tx][i]);
}

// ---------------------------------------------------------------------------
// R11: R10's packed bf16x2 pool, bin-split for occupancy.
// R10 was grid-limited: 512 blocks = exactly 2 blocks/CU = 16 waves/CU, and
// each wave ran ~3 serial pair-iterations gated by scattered L2/L3 tap
// latency (~600-900 cy, strides 512 B / 32 KB). R11 splits the 49 bins into
// two groups (25 + 24) per channel-half: grid N*4 = 1024 blocks x 512 thr,
// LDS 29 KB -> ~15 KB, __launch_bounds__(512,6) caps VGPR so 3 blocks/CU
// (24 waves/CU) are resident -> +50% TLP to hide tap latency.
// Geometry + FMA order bit-identical to R10 (same descriptor build, same
// pair/tail schedule within a group) -> absmax unchanged.
// Phase 3: per-channel row copy (4 threads/row, 25 floats @ out[c][g*25..])
// - rows are written contiguously and temporally adjacent, so L2 write-
// combining keeps WRITE_SIZE at the ideal 12.8 MB.
// ---------------------------------------------------------------------------
__global__ __launch_bounds__(512, 6) void pool_packed_bf16(const ushort_t* __restrict__ src, // NHWC bf16
                                                           const float* __restrict__ rois,
                                                           const float* __restrict__ offset,
                                                           float* __restrict__ out,
                                                           int N) {
    __shared__ float lds[CH * NB0];          // <= 128*25 floats = 12.5 KB
    __shared__ int   sdesc[NB0 * DESC_DW];   // 2.0 KB
    const int n    = blockIdx.x >> 2;
    const int h    = (blockIdx.x >> 1) & 1;  // channel half: 0 -> ch 0..127, 1 -> 128..255
    const int g    = blockIdx.x & 1;         // bin group: 0 -> bins 0..24, 1 -> bins 25..48
    const int nb   = g ? NB1 : NB0;
    const int bin0 = g * NB0;
    const int t    = threadIdx.x;
    const int wave = t >> 6;                 // 0..7
    const int lane = t & 63;

    // ---- phase 1: lanes 0..nb-1 (wave 0) build this group's descriptors ----
    if (t < nb) {
        const int bin = bin0 + t;            // global bin
        const int ph = bin / POOLED;
        const int pw = bin - ph * POOLED;

        const float* roi = rois + (size_t)n * 5;
        const int b = (int)roi[0];

        const float roi_sw = rintf(roi[1]) * SPATIAL_SCALE - 0.5f;
        const float roi_sh = rintf(roi[2]) * SPATIAL_SCALE - 0.5f;
        const float roi_ew = (rintf(roi[3]) + 1.0f) * SPATIAL_SCALE - 0.5f;
        const float roi_eh = (rintf(roi[4]) + 1.0f) * SPATIAL_SCALE - 0.5f;
        const float roi_w = fmaxf(roi_ew - roi_sw, 0.1f);
        const float roi_h = fmaxf(roi_eh - roi_sh, 0.1f);
        const float bin_w = roi_w / (float)POOLED;
        const float bin_h = roi_h / (float)POOLED;
        const float sub_w = bin_w / (float)SAMPLES;
        const float sub_h = bin_h / (float)SAMPLES;

        int part_h = (int)floorf(((float)ph / (float)POOLED) * (float)PART);
        int part_w = (int)floorf(((float)pw / (float)POOLED) * (float)PART);
        part_h = min(max(part_h, 0), PART - 1);
        part_w = min(max(part_w, 0), PART - 1);

        const float tx = offset[(((size_t)n * 2 + 0) * PART + part_h) * PART + part_w] * TRANS_STD;
        const float ty = offset[(((size_t)n * 2 + 1) * PART + part_h) * PART + part_w] * TRANS_STD;

        const float wstart = (float)pw * bin_w + roi_sw + tx * roi_w;
        const float hstart = (float)ph * bin_h + roi_sh + ty * roi_h;

        float Wx[4] = {0.f, 0.f, 0.f, 0.f};
        int xmin = 0, nvw = 0;
        #pragma unroll
        for (int sw = 0; sw < SAMPLES; ++sw) {
            const float w = wstart + (float)sw * sub_w;
            if (w > -0.5f && w < (float)W_DIM - 0.5f) {
                const float wc = fminf(fmaxf(w, 0.0f), (float)(W_DIM - 1));
                const int x0 = (int)floorf(wc);
                const int x1 = min(x0 + 1, W_DIM - 1);
                const float dx = wc - (float)x0;
                if (nvw == 0) xmin = x0;
                ++nvw;
                const int i0 = x0 - xmin;
                const int i1 = x1 - xmin;
                const float w0 = 1.0f - dx;
                Wx[0] += (i0 == 0 ? w0 : 0.f) + (i1 == 0 ? dx : 0.f);
                Wx[1] += (i0 == 1 ? w0 : 0.f) + (i1 == 1 ? dx : 0.f);
                Wx[2] += (i0 == 2 ? w0 : 0.f) + (i1 == 2 ? dx : 0.f);
                Wx[3] += (i1 == 3 ? dx : 0.f);
            }
        }

        float Wy[4] = {0.f, 0.f, 0.f, 0.f};
        int ymin = 0, nvh = 0;
        #pragma unroll
        for (int sh = 0; sh < SAMPLES; ++sh) {
            const float hh = hstart + (float)sh * sub_h;
            if (hh > -0.5f && hh < (float)H_DIM - 0.5f) {
                const float hc = fminf(fmaxf(hh, 0.0f), (float)(H_DIM - 1));
                const int y0 = (int)floorf(hc);
                const int y1 = min(y0 + 1, H_DIM - 1);
                const float dy = hc - (float)y0;
                if (nvh == 0) ymin = y0;
                ++nvh;
                const int i0 = y0 - ymin;
                const int i1 = y1 - ymin;
                const float w0 = 1.0f - dy;
                Wy[0] += (i0 == 0 ? w0 : 0.f) + (i1 == 0 ? dy : 0.f);
                Wy[1] += (i0 == 1 ? w0 : 0.f) + (i1 == 1 ? dy : 0.f);
                Wy[2] += (i0 == 2 ? w0 : 0.f) + (i1 == 2 ? dy : 0.f);
                Wy[3] += (i1 == 3 ? dy : 0.f);
            }
        }

        const int cnt = nvw * nvh;
        const float rinv = (cnt > 0) ? 1.0f / (float)cnt : 0.0f;   // guard 0*inf

        int* d = sdesc + t * DESC_DW;
        d[0] = ((b * H_DIM + ymin) * W_DIM + xmin) * C_DIM;        // element offset (even)
        float* wp = (float*)(d + 4);
        #pragma unroll
        for (int iy = 0; iy < 4; ++iy)
            #pragma unroll
            for (int ix = 0; ix < 4; ++ix)
                wp[iy * 4 + ix] = Wy[iy] * Wx[ix] * rinv;          // exact 0 outside footprint
    }

    __syncthreads();

    // ---- phase 2: pool, lane = channels {h*128+2*lane, +1}, 2 bins/iter ----
    const ushort_t* srch = src + h * CH + 2 * lane;   // even element offset -> uint-aligned

    int bin = wave;                                   // local bin within group
    for (; bin + 8 < nb; bin += 16) {
        const int bin2 = bin + 8;
        const int* d1 = sdesc + bin  * DESC_DW;
        const int* d2 = sdesc + bin2 * DESC_DW;
        const float* w1 = (const float*)(d1 + 4);
        const float* w2 = (const float*)(d2 + 4);
        const uint_t* p1 = (const uint_t*)(srch + d1[0]);
        const uint_t* p2 = (const uint_t*)(srch + d2[0]);

        uint_t v1[16], v2[16];
        #pragma unroll
        for (int iy = 0; iy < 4; ++iy)
            #pragma unroll
            for (int ix = 0; ix < 4; ++ix) {
                v1[iy * 4 + ix] = p1[(iy * (W_DIM * C_DIM) + ix * C_DIM) >> 1];
                v2[iy * 4 + ix] = p2[(iy * (W_DIM * C_DIM) + ix * C_DIM) >> 1];
            }

        float a1l = 0.f, a1h = 0.f, a2l = 0.f, a2h = 0.f;
        #pragma unroll
        for (int k = 0; k < 16; ++k) {
            const uint_t u1 = v1[k], u2 = v2[k];
            a1l = fmaf(w1[k], __uint_as_float(u1 << 16),          a1l);
            a1h = fmaf(w1[k], __uint_as_float(u1 & 0xFFFF0000u),  a1h);
            a2l = fmaf(w2[k], __uint_as_float(u2 << 16),          a2l);
            a2h = fmaf(w2[k], __uint_as_float(u2 & 0xFFFF0000u),  a2h);
        }
        lds[(2 * lane    ) * nb + bin ] = a1l;
        lds[(2 * lane + 1) * nb + bin ] = a1h;
        lds[(2 * lane    ) * nb + bin2] = a2l;
        lds[(2 * lane + 1) * nb + bin2] = a2h;
    }
    if (bin < nb) {   // tail
        const int* d1 = sdesc + bin * DESC_DW;
        const float* w1 = (const float*)(d1 + 4);
        const uint_t* p1 = (const uint_t*)(srch + d1[0]);
        uint_t v1[16];
        #pragma unroll
        for (int iy = 0; iy < 4; ++iy)
            #pragma unroll
            for (int ix = 0; ix < 4; ++ix)
                v1[iy * 4 + ix] = p1[(iy * (W_DIM * C_DIM) + ix * C_DIM) >> 1];
        float a1l = 0.f, a1h = 0.f;
        #pragma unroll
        for (int k = 0; k < 16; ++k) {
            const uint_t u1 = v1[k];
            a1l = fmaf(w1[k], __uint_as_float(u1 << 16),         a1l);
            a1h = fmaf(w1[k], __uint_as_float(u1 & 0xFFFF0000u), a1h);
        }
        lds[(2 * lane    ) * nb + bin] = a1l;
        lds[(2 * lane + 1) * nb + bin] = a1h;
    }

    __syncthreads();

    // ---- phase 3: row copy: lds[c][binL] -> out[n][h*128+c][bin0+binL] ----
    // 4 threads per channel row: thread writes elems sub, sub+4, ... of the
    // nb-float row. Rows are 100/96 B and written temporally adjacent ->
    // L2 write-combines to full lines.
    {
        float* ob = out + (size_t)n * (C_DIM * BINS) + (size_t)h * (CH * BINS) + bin0;
        const int c   = t >> 2;       // 0..127
        const int sub = t & 3;
        const float* lr = lds + c * nb;
        float*       orow = ob + (size_t)c * BINS;
        for (int j = sub; j < nb; j += 4)
            orow[j] = lr[j];
    }
}

// ---------------------------------------------------------------------------
// Fallback: direct NCHW fp32 gather (only if workspace too small).
// ---------------------------------------------------------------------------
__global__ __launch_bounds__(256) void deform_roi_pool_nchw(const float* __restrict__ src,
                                                            const float* __restrict__ rois,
                                                            const float* __restrict__ offset,
                                                            float* __restrict__ out,
                                                            int N) {
    const int blk = blockIdx.x;
    const int n   = blk / BINS;
    const int bin = blk % BINS;
    const int ph  = bin / POOLED;
    const int pw  = bin % POOLED;
    const int c   = threadIdx.x;
    if (n >= N) return;

    const float* roi = rois + (size_t)n * 5;
    const int b = (int)roi[0];

    const float roi_sw = rintf(roi[1]) * SPATIAL_SCALE - 0.5f;
    const float roi_sh = rintf(roi[2]) * SPATIAL_SCALE - 0.5f;
    const float roi_ew = (rintf(roi[3]) + 1.0f) * SPATIAL_SCALE - 0.5f;
    const float roi_eh = (rintf(roi[4]) + 1.0f) * SPATIAL_SCALE - 0.5f;
    const float roi_w = fmaxf(roi_ew - roi_sw, 0.1f);
    const float roi_h = fmaxf(roi_eh - roi_sh, 0.1f);
    const float bin_w = roi_w / (float)POOLED;
    const float bin_h = roi_h / (float)POOLED;
    const float sub_w = bin_w / (float)SAMPLES;
    const float sub_h = bin_h / (float)SAMPLES;

    int part_h = (int)floorf(((float)ph / (float)POOLED) * (float)PART);
    int part_w = (int)floorf(((float)pw / (float)POOLED) * (float)PART);
    part_h = min(max(part_h, 0), PART - 1);
    part_w = min(max(part_w, 0), PART - 1);

    const float tx = offset[(((size_t)n * 2 + 0) * PART + part_h) * PART + part_w] * TRANS_STD;
    const float ty = offset[(((size_t)n * 2 + 1) * PART + part_h) * PART + part_w] * TRANS_STD;

    const float wstart = (float)pw * bin_w + roi_sw + tx * roi_w;
    const float hstart = (float)ph * bin_h + roi_sh + ty * roi_h;

    float sum = 0.0f;
    int cnt = 0;

    #pragma unroll
    for (int sh = 0; sh < SAMPLES; ++sh) {
        const float h = hstart + (float)sh * sub_h;
        #pragma unroll
        for (int sw = 0; sw < SAMPLES; ++sw) {
            const float w = wstart + (float)sw * sub_w;
            const bool valid = (w > -0.5f) && (w < (float)W_DIM - 0.5f) &&
                               (h > -0.5f) && (h < (float)H_DIM - 0.5f);
            if (!valid) continue;
            ++cnt;
            const float wc = fminf(fmaxf(w, 0.0f), (float)(W_DIM - 1));
            const float hc = fminf(fmaxf(h, 0.0f), (float)(H_DIM - 1));
            const int x0 = (int)floorf(wc);
            const int y0 = (int)floorf(hc);
            const int x1 = min(x0 + 1, W_DIM - 1);
            const int y1 = min(y0 + 1, H_DIM - 1);
            const float dx = wc - (float)x0;
            const float dy = hc - (float)y0;

            const size_t base = ((size_t)b * C_DIM + c) * (H_DIM * W_DIM);
            const float v00 = src[base + (size_t)y0 * W_DIM + x0];
            const float v01 = src[base + (size_t)y0 * W_DIM + x1];
            const float v10 = src[base + (size_t)y1 * W_DIM + x0];
            const float v11 = src[base + (size_t)y1 * W_DIM + x1];
            sum += (1.0f - dx) * (1.0f - dy) * v00
                 + (1.0f - dx) * dy          * v10
                 + dx          * (1.0f - dy) * v01
                 + dx          * dy          * v11;
        }
    }

    const float res = (cnt > 0) ? sum / (float)cnt : 0.0f;
    out[(((size_t)n * C_DIM + c) * POOLED + ph) * POOLED + pw] = res;
}

extern "C" void kernel_launch(void* const* d_in, const int* in_sizes, int n_in,
                              void* d_out, int out_size, void* d_ws, size_t ws_size,
                              hipStream_t stream) {
    const float* data   = (const float*)d_in[0];
    const float* rois   = (const float*)d_in[1];
    const float* offset = (const float*)d_in[2];
    float* out = (float*)d_out;
    const int N = in_sizes[1] / 5;

    const size_t nhwc_bf16_bytes = (size_t)B_DIM * C_DIM * H_DIM * W_DIM * sizeof(ushort_t);
    // unconditional 4x4 taps may overread ~100 KB past the bf16 image
    // (zero-weighted; 0xAA poison decodes to finite bf16). 1 MB margin.
    const size_t margin = 1u << 20;

    if (ws_size >= nhwc_bf16_bytes + margin) {
        ushort_t* data_t = (ushort_t*)d_ws;
        dim3 tb(32, 8, 1);
        dim3 tg((H_DIM * W_DIM) / TS, C_DIM / TS, B_DIM);
        nchw_to_nhwc_bf16<<<tg, tb, 0, stream>>>(data, data_t);
        pool_packed_bf16<<<N * 4, 512, 0, stream>>>(data_t, rois, offset, out, N);
    } else {
        deform_roi_pool_nchw<<<N * BINS, C_DIM, 0, stream>>>(
            data, rois, offset, out, N);
    }
}

// Round 2
// 80.310 us; speedup vs baseline: 1.0352x; 1.0352x over previous
//
#include <hip/hip_runtime.h>
#include <hip/hip_bf16.h>

#define SPATIAL_SCALE 0.125f
#define POOLED 7
#define PART 7
#define SAMPLES 4
#define TRANS_STD 0.1f

#define B_DIM 4
#define C_DIM 256
#define H_DIM 64
#define W_DIM 64
#define BINS (POOLED * POOLED)   // 49
#define CH 128                   // channels per pool block (half)
#define DESC_DW 20               // LDS descriptor stride: rowbase, small, pad x2, w[16]

typedef unsigned short ushort_t;
typedef unsigned int   uint_t;

// round-to-nearest-even fp32 -> bf16 (manual; finite inputs)
__device__ __forceinline__ ushort_t f2bf_rne(float f) {
    uint_t x = __float_as_uint(f);
    x += 0x7FFFu + ((x >> 16) & 1u);
    return (ushort_t)(x >> 16);
}

// ---------------------------------------------------------------------------
// NCHW fp32 -> NHWC bf16 transpose (proven R9; ~24 MB traffic, ~4.5 us)
// ---------------------------------------------------------------------------
#define TS 32
__global__ __launch_bounds__(256) void nchw_to_nhwc_bf16(const float* __restrict__ in,
                                                         ushort_t* __restrict__ out) {
    __shared__ float tile[TS][TS + 1];
    const int b   = blockIdx.z;
    const int hw0 = blockIdx.x * TS;
    const int c0  = blockIdx.y * TS;
    const int tx  = threadIdx.x;
    const int ty  = threadIdx.y;

    const float* inb  = in  + (size_t)b * C_DIM * (H_DIM * W_DIM);
    ushort_t*    outb = out + (size_t)b * (H_DIM * W_DIM) * C_DIM;

    #pragma unroll
    for (int i = ty; i < TS; i += 8)
        tile[i][tx] = inb[(size_t)(c0 + i) * (H_DIM * W_DIM) + (hw0 + tx)];
    __syncthreads();
    #pragma unroll
    for (int i = ty; i < TS; i += 8)
        outb[(size_t)(hw0 + i) * C_DIM + (c0 + tx)] = f2bf_rne(tile[tx][i]);
}

// ---------------------------------------------------------------------------
// R12: exact R10 structure (grid N*2, 512 thr, contiguous float4 writeback --
// R11's bin-split regressed 80.5->83.1, falsifying the latency-bound theory),
// plus a 3x3 tap fast path.
// Dataset bound: roi_w <= 14.125 feature px -> bin_w <= 2.02 -> sample span
// 0.75*bin_w < 2 -> bilinear support is at most 3 columns and 3 rows for
// EVERY bin. The 4th row/col weights are exactly 0.0f, and fmaf(0*v,acc)=acc
// exactly, so skipping them is bit-identical (absmax unchanged). Descriptor
// stores small=(ncols<=3 && nrows<=3); phase 2 branches on the wave-uniform
// flag (readfirstlane -> scalar branch): 18 loads/pair-iter instead of 32.
// 4x4 safety path kept for out-of-model ROIs.
// ---------------------------------------------------------------------------
__global__ __launch_bounds__(512) void pool_packed_bf16(const ushort_t* __restrict__ src, // NHWC bf16
                                                        const float* __restrict__ rois,
                                                        const float* __restrict__ offset,
                                                        float* __restrict__ out,
                                                        int N) {
    __shared__ float lds[CH * BINS];        // 6272 floats = 25 KB
    __shared__ int   sdesc[BINS * DESC_DW]; // 3.9 KB
    const int n    = blockIdx.x >> 1;
    const int h    = blockIdx.x & 1;        // channel half: 0 -> ch 0..127, 1 -> 128..255
    const int t    = threadIdx.x;
    const int wave = t >> 6;                // 0..7
    const int lane = t & 63;

    // ---- phase 1: lanes 0..48 (wave 0) build all 49 bin descriptors ----
    if (t < BINS) {
        const int bin = t;
        const int ph = bin / POOLED;
        const int pw = bin - ph * POOLED;

        const float* roi = rois + (size_t)n * 5;
        const int b = (int)roi[0];

        const float roi_sw = rintf(roi[1]) * SPATIAL_SCALE - 0.5f;
        const float roi_sh = rintf(roi[2]) * SPATIAL_SCALE - 0.5f;
        const float roi_ew = (rintf(roi[3]) + 1.0f) * SPATIAL_SCALE - 0.5f;
        const float roi_eh = (rintf(roi[4]) + 1.0f) * SPATIAL_SCALE - 0.5f;
        const float roi_w = fmaxf(roi_ew - roi_sw, 0.1f);
        const float roi_h = fmaxf(roi_eh - roi_sh, 0.1f);
        const float bin_w = roi_w / (float)POOLED;
        const float bin_h = roi_h / (float)POOLED;
        const float sub_w = bin_w / (float)SAMPLES;
        const float sub_h = bin_h / (float)SAMPLES;

        int part_h = (int)floorf(((float)ph / (float)POOLED) * (float)PART);
        int part_w = (int)floorf(((float)pw / (float)POOLED) * (float)PART);
        part_h = min(max(part_h, 0), PART - 1);
        part_w = min(max(part_w, 0), PART - 1);

        const float tx = offset[(((size_t)n * 2 + 0) * PART + part_h) * PART + part_w] * TRANS_STD;
        const float ty = offset[(((size_t)n * 2 + 1) * PART + part_h) * PART + part_w] * TRANS_STD;

        const float wstart = (float)pw * bin_w + roi_sw + tx * roi_w;
        const float hstart = (float)ph * bin_h + roi_sh + ty * roi_h;

        float Wx[4] = {0.f, 0.f, 0.f, 0.f};
        int xmin = 0, xmax = 0, nvw = 0;
        #pragma unroll
        for (int sw = 0; sw < SAMPLES; ++sw) {
            const float w = wstart + (float)sw * sub_w;
            if (w > -0.5f && w < (float)W_DIM - 0.5f) {
                const float wc = fminf(fmaxf(w, 0.0f), (float)(W_DIM - 1));
                const int x0 = (int)floorf(wc);
                const int x1 = min(x0 + 1, W_DIM - 1);
                const float dx = wc - (float)x0;
                if (nvw == 0) xmin = x0;   // w monotone increasing -> first is min
                xmax = x1;                  // last valid has the max x1
                ++nvw;
                const int i0 = x0 - xmin;
                const int i1 = x1 - xmin;
                const float w0 = 1.0f - dx;
                Wx[0] += (i0 == 0 ? w0 : 0.f) + (i1 == 0 ? dx : 0.f);
                Wx[1] += (i0 == 1 ? w0 : 0.f) + (i1 == 1 ? dx : 0.f);
                Wx[2] += (i0 == 2 ? w0 : 0.f) + (i1 == 2 ? dx : 0.f);
                Wx[3] += (i1 == 3 ? dx : 0.f);
            }
        }

        float Wy[4] = {0.f, 0.f, 0.f, 0.f};
        int ymin = 0, ymax = 0, nvh = 0;
        #pragma unroll
        for (int sh = 0; sh < SAMPLES; ++sh) {
            const float hh = hstart + (float)sh * sub_h;
            if (hh > -0.5f && hh < (float)H_DIM - 0.5f) {
                const float hc = fminf(fmaxf(hh, 0.0f), (float)(H_DIM - 1));
                const int y0 = (int)floorf(hc);
                const int y1 = min(y0 + 1, H_DIM - 1);
                const float dy = hc - (float)y0;
                if (nvh == 0) ymin = y0;
                ymax = y1;
                ++nvh;
                const int i0 = y0 - ymin;
                const int i1 = y1 - ymin;
                const float w0 = 1.0f - dy;
                Wy[0] += (i0 == 0 ? w0 : 0.f) + (i1 == 0 ? dy : 0.f);
                Wy[1] += (i0 == 1 ? w0 : 0.f) + (i1 == 1 ? dy : 0.f);
                Wy[2] += (i0 == 2 ? w0 : 0.f) + (i1 == 2 ? dy : 0.f);
                Wy[3] += (i1 == 3 ? dy : 0.f);
            }
        }

        const int cnt = nvw * nvh;
        const float rinv = (cnt > 0) ? 1.0f / (float)cnt : 0.0f;   // guard 0*inf

        const int ncols = xmax - xmin + 1;   // 1..4 (nvw==0 -> 1)
        const int nrows = ymax - ymin + 1;

        int* d = sdesc + bin * DESC_DW;
        d[0] = ((b * H_DIM + ymin) * W_DIM + xmin) * C_DIM;        // element offset (even)
        d[1] = (ncols <= 3 && nrows <= 3) ? 1 : 0;                 // 3x3 support flag
        float* wp = (float*)(d + 4);
        #pragma unroll
        for (int iy = 0; iy < 4; ++iy)
            #pragma unroll
            for (int ix = 0; ix < 4; ++ix)
                wp[iy * 4 + ix] = Wy[iy] * Wx[ix] * rinv;          // exact 0 outside footprint
    }

    __syncthreads();

    // ---- phase 2: pool, lane = channels {h*128+2*lane, +1}, 2 bins/iter ----
    const ushort_t* srch = src + h * CH + 2 * lane;   // even element offset -> uint-aligned

    int bin = wave;
    for (; bin + 8 < BINS; bin += 16) {
        const int bin2 = bin + 8;
        const int* d1 = sdesc + bin  * DESC_DW;
        const int* d2 = sdesc + bin2 * DESC_DW;
        const float* w1 = (const float*)(d1 + 4);
        const float* w2 = (const float*)(d2 + 4);
        const uint_t* p1 = (const uint_t*)(srch + d1[0]);
        const uint_t* p2 = (const uint_t*)(srch + d2[0]);

        float a1l = 0.f, a1h = 0.f, a2l = 0.f, a2h = 0.f;
        const int small = __builtin_amdgcn_readfirstlane(d1[1] & d2[1]);  // wave-uniform
        if (small) {
            // 3x3 fast path: always taken for this dataset's ROI sizes.
            // Same lexicographic (iy,ix) order over the nonzero-weight taps
            // as the 4x4 path -> bit-identical accumulation.
            uint_t v1[9], v2[9];
            #pragma unroll
            for (int iy = 0; iy < 3; ++iy)
                #pragma unroll
                for (int ix = 0; ix < 3; ++ix) {
                    v1[iy * 3 + ix] = p1[(iy * (W_DIM * C_DIM) + ix * C_DIM) >> 1];
                    v2[iy * 3 + ix] = p2[(iy * (W_DIM * C_DIM) + ix * C_DIM) >> 1];
                }
            #pragma unroll
            for (int iy = 0; iy < 3; ++iy)
                #pragma unroll
                for (int ix = 0; ix < 3; ++ix) {
                    const int k = iy * 4 + ix;          // weight index (4x4 table)
                    const uint_t u1 = v1[iy * 3 + ix], u2 = v2[iy * 3 + ix];
                    a1l = fmaf(w1[k], __uint_as_float(u1 << 16),          a1l);
                    a1h = fmaf(w1[k], __uint_as_float(u1 & 0xFFFF0000u),  a1h);
                    a2l = fmaf(w2[k], __uint_as_float(u2 << 16),          a2l);
                    a2h = fmaf(w2[k], __uint_as_float(u2 & 0xFFFF0000u),  a2h);
                }
        } else {
            // 4x4 safety path (out-of-model ROI sizes)
            uint_t v1[16], v2[16];
            #pragma unroll
            for (int iy = 0; iy < 4; ++iy)
                #pragma unroll
                for (int ix = 0; ix < 4; ++ix) {
                    v1[iy * 4 + ix] = p1[(iy * (W_DIM * C_DIM) + ix * C_DIM) >> 1];
                    v2[iy * 4 + ix] = p2[(iy * (W_DIM * C_DIM) + ix * C_DIM) >> 1];
                }
            #pragma unroll
            for (int k = 0; k < 16; ++k) {
                const uint_t u1 = v1[k], u2 = v2[k];
                a1l = fmaf(w1[k], __uint_as_float(u1 << 16),          a1l);
                a1h = fmaf(w1[k], __uint_as_float(u1 & 0xFFFF0000u),  a1h);
                a2l = fmaf(w2[k], __uint_as_float(u2 << 16),          a2l);
                a2h = fmaf(w2[k], __uint_as_float(u2 & 0xFFFF0000u),  a2h);
            }
        }
        lds[(2 * lane    ) * BINS + bin ] = a1l;
        lds[(2 * lane + 1) * BINS + bin ] = a1h;
        lds[(2 * lane    ) * BINS + bin2] = a2l;
        lds[(2 * lane + 1) * BINS + bin2] = a2h;
    }
    if (bin < BINS) {   // tail (wave 0: bin 48)
        const int* d1 = sdesc + bin * DESC_DW;
        const float* w1 = (const float*)(d1 + 4);
        const uint_t* p1 = (const uint_t*)(srch + d1[0]);
        float a1l = 0.f, a1h = 0.f;
        const int small = __builtin_amdgcn_readfirstlane(d1[1]);
        if (small) {
            uint_t v1[9];
            #pragma unroll
            for (int iy = 0; iy < 3; ++iy)
                #pragma unroll
                for (int ix = 0; ix < 3; ++ix)
                    v1[iy * 3 + ix] = p1[(iy * (W_DIM * C_DIM) + ix * C_DIM) >> 1];
            #pragma unroll
            for (int iy = 0; iy < 3; ++iy)
                #pragma unroll
                for (int ix = 0; ix < 3; ++ix) {
                    const int k = iy * 4 + ix;
                    const uint_t u1 = v1[iy * 3 + ix];
                    a1l = fmaf(w1[k], __uint_as_float(u1 << 16),         a1l);
                    a1h = fmaf(w1[k], __uint_as_float(u1 & 0xFFFF0000u), a1h);
                }
        } else {
            uint_t v1[16];
            #pragma unroll
            for (int iy = 0; iy < 4; ++iy)
                #pragma unroll
                for (int ix = 0; ix < 4; ++ix)
                    v1[iy * 4 + ix] = p1[(iy * (W_DIM * C_DIM) + ix * C_DIM) >> 1];
            #pragma unroll
            for (int k = 0; k < 16; ++k) {
                const uint_t u1 = v1[k];
                a1l = fmaf(w1[k], __uint_as_float(u1 << 16),         a1l);
                a1h = fmaf(w1[k], __uint_as_float(u1 & 0xFFFF0000u), a1h);
            }
        }
        lds[(2 * lane    ) * BINS + bin] = a1l;
        lds[(2 * lane + 1) * BINS + bin] = a1h;
    }

    __syncthreads();

    // ---- phase 3: identity writeback: lds [c][bin] == out[n] [c][ph][pw] ----
    float4* on4 = (float4*)(out + (size_t)n * (C_DIM * BINS) + (size_t)h * (CH * BINS));
    const float4* ls4 = (const float4*)lds;
    for (int j = t; j < (CH * BINS) / 4; j += 512)
        on4[j] = ls4[j];
}

// ---------------------------------------------------------------------------
// Fallback: direct NCHW fp32 gather (only if workspace too small).
// ---------------------------------------------------------------------------
__global__ __launch_bounds__(256) void deform_roi_pool_nchw(const float* __restrict__ src,
                                                            const float* __restrict__ rois,
                                                            const float* __restrict__ offset,
                                                            float* __restrict__ out,
                                                            int N) {
    const int blk = blockIdx.x;
    const int n   = blk / BINS;
    const int bin = blk % BINS;
    const int ph  = bin / POOLED;
    const int pw  = bin % POOLED;
    const int c   = threadIdx.x;
    if (n >= N) return;

    const float* roi = rois + (size_t)n * 5;
    const int b = (int)roi[0];

    const float roi_sw = rintf(roi[1]) * SPATIAL_SCALE - 0.5f;
    const float roi_sh = rintf(roi[2]) * SPATIAL_SCALE - 0.5f;
    const float roi_ew = (rintf(roi[3]) + 1.0f) * SPATIAL_SCALE - 0.5f;
    const float roi_eh = (rintf(roi[4]) + 1.0f) * SPATIAL_SCALE - 0.5f;
    const float roi_w = fmaxf(roi_ew - roi_sw, 0.1f);
    const float roi_h = fmaxf(roi_eh - roi_sh, 0.1f);
    const float bin_w = roi_w / (float)POOLED;
    const float bin_h = roi_h / (float)POOLED;
    const float sub_w = bin_w / (float)SAMPLES;
    const float sub_h = bin_h / (float)SAMPLES;

    int part_h = (int)floorf(((float)ph / (float)POOLED) * (float)PART);
    int part_w = (int)floorf(((float)pw / (float)POOLED) * (float)PART);
    part_h = min(max(part_h, 0), PART - 1);
    part_w = min(max(part_w, 0), PART - 1);

    const float tx = offset[(((size_t)n * 2 + 0) * PART + part_h) * PART + part_w] * TRANS_STD;
    const float ty = offset[(((size_t)n * 2 + 1) * PART + part_h) * PART + part_w] * TRANS_STD;

    const float wstart = (float)pw * bin_w + roi_sw + tx * roi_w;
    const float hstart = (float)ph * bin_h + roi_sh + ty * roi_h;

    float sum = 0.0f;
    int cnt = 0;

    #pragma unroll
    for (int sh = 0; sh < SAMPLES; ++sh) {
        const float h = hstart + (float)sh * sub_h;
        #pragma unroll
        for (int sw = 0; sw < SAMPLES; ++sw) {
            const float w = wstart + (float)sw * sub_w;
            const bool valid = (w > -0.5f) && (w < (float)W_DIM - 0.5f) &&
                               (h > -0.5f) && (h < (float)H_DIM - 0.5f);
            if (!valid) continue;
            ++cnt;
            const float wc = fminf(fmaxf(w, 0.0f), (float)(W_DIM - 1));
            const float hc = fminf(fmaxf(h, 0.0f), (float)(H_DIM - 1));
            const int x0 = (int)floorf(wc);
            const int y0 = (int)floorf(hc);
            const int x1 = min(x0 + 1, W_DIM - 1);
            const int y1 = min(y0 + 1, H_DIM - 1);
            const float dx = wc - (float)x0;
            const float dy = hc - (float)y0;

            const size_t base = ((size_t)b * C_DIM + c) * (H_DIM * W_DIM);
            const float v00 = src[base + (size_t)y0 * W_DIM + x0];
            const float v01 = src[base + (size_t)y0 * W_DIM + x1];
            const float v10 = src[base + (size_t)y1 * W_DIM + x0];
            const float v11 = src[base + (size_t)y1 * W_DIM + x1];
            sum += (1.0f - dx) * (1.0f - dy) * v00
                 + (1.0f - dx) * dy          * v10
                 + dx          * (1.0f - dy) * v01
                 + dx          * dy          * v11;
        }
    }

    const float res = (cnt > 0) ? sum / (float)cnt : 0.0f;
    out[(((size_t)n * C_DIM + c) * POOLED + ph) * POOLED + pw] = res;
}

extern "C" void kernel_launch(void* const* d_in, const int* in_sizes, int n_in,
                              void* d_out, int out_size, void* d_ws, size_t ws_size,
                              hipStream_t stream) {
    const float* data   = (const float*)d_in[0];
    const float* rois   = (const float*)d_in[1];
    const float* offset = (const float*)d_in[2];
    float* out = (float*)d_out;
    const int N = in_sizes[1] / 5;

    const size_t nhwc_bf16_bytes = (size_t)B_DIM * C_DIM * H_DIM * W_DIM * sizeof(ushort_t);
    // unconditional 4x4 taps may overread ~100 KB past the bf16 image
    // (zero-weighted; 0xAA poison decodes to finite bf16). 1 MB margin.
    const size_t margin = 1u << 20;

    if (ws_size >= nhwc_bf16_bytes + margin) {
        ushort_t* data_t = (ushort_t*)d_ws;
        dim3 tb(32, 8, 1);
        dim3 tg((H_DIM * W_DIM) / TS, C_DIM / TS, B_DIM);
        nchw_to_nhwc_bf16<<<tg, tb, 0, stream>>>(data, data_t);
        pool_packed_bf16<<<N * 2, 512, 0, stream>>>(data_t, rois, offset, out, N);
    } else {
        deform_roi_pool_nchw<<<N * BINS, C_DIM, 0, stream>>>(
            data, rois, offset, out, N);
    }
}